// Round 1
// baseline (254.255 us; speedup 1.0000x reference)
//
#include <hip/hip_runtime.h>

// Problem constants (fixed by the reference).
#define N_NODES 50000
#define N_EDGES 800000
#define X_DIM 128
#define H_DIM 256
#define Y_DIM 128

typedef unsigned int uint32;
typedef unsigned short ushort16;
typedef __attribute__((ext_vector_type(8))) short short8;
typedef __attribute__((ext_vector_type(4))) float floatx4;

// bf16 helpers (round-to-nearest-even)
__device__ inline ushort16 f2bf(float f) {
    uint32 u = __float_as_uint(f);
    return (ushort16)((u + 0x7FFFu + ((u >> 16) & 1u)) >> 16);
}
__device__ inline float bf_lo(uint32 u) { return __uint_as_float(u << 16); }
__device__ inline float bf_hi(uint32 u) { return __uint_as_float(u & 0xFFFF0000u); }

// Bucket geometry: 391 buckets of 128 rows; 196 chunks of 4096 edges.
#define BUCKET_SHIFT 7
#define NB 391              // ceil(50000/128)
#define CHUNK 4096
#define NCHUNK 196          // ceil(800000/4096)
#define CAP_B 2560          // LDS capacity per bucket (mean 2046)

// Column panels for L2 blocking of the gathers: 4 panels of 12512 cols.
// One panel of a bf16 [50000 x 128] table = 12512*256B = 3.2 MB -> fits the
// 4 MB per-XCD L2. All co-resident blocks walk panels in the same order.
#define PS 12512
__device__ inline int panel_of(int col) {
    return (col >= 2 * PS) ? ((col >= 3 * PS) ? 3 : 2) : ((col >= PS) ? 1 : 0);
}

#define NORM_BLOCKS 12500   // N_NODES*64/256
#define CONV_BLOCKS 256     // 65536/256

// ---------------------------------------------------------------------------
// Prep (fused): row-normalize x -> bf16; transpose-convert W1,W2 to bf16;
// per-chunk bucket histograms -> gpartial[chunk][bucket] (no global atomics).
// ---------------------------------------------------------------------------
__global__ __launch_bounds__(256) void prep_kernel(
    const float* __restrict__ x, uint32* __restrict__ xb,
    const float* __restrict__ W1, const float* __restrict__ W2,
    ushort16* __restrict__ W1t, ushort16* __restrict__ W2t,
    const int* __restrict__ rows, int* __restrict__ gpartial) {
    int b = blockIdx.x;
    if (b < NORM_BLOCKS) {
        int row = (b * 256 + threadIdx.x) >> 6;  // exact: 12500*4 = 50000 rows
        int lane = threadIdx.x & 63;
        float2 v = ((const float2*)x)[(size_t)row * 64 + lane];
        float s = v.x + v.y;
        #pragma unroll
        for (int off = 32; off > 0; off >>= 1) s += __shfl_xor(s, off, 64);
        float inv = 1.0f / (s + 1e-4f);
        uint32 lo = (uint32)f2bf(v.x * inv);
        uint32 hi = (uint32)f2bf(v.y * inv);
        xb[(size_t)row * 64 + lane] = lo | (hi << 16);
    } else if (b < NORM_BLOCKS + CONV_BLOCKS) {
        int t = (b - NORM_BLOCKS) * 256 + threadIdx.x;  // 0..65535
        if (t < X_DIM * H_DIM) {
            int n = t >> 7, k = t & 127;           // W1t[n][k] = W1[k][n]
            W1t[t] = f2bf(W1[k * H_DIM + n]);
        } else {
            int u = t - X_DIM * H_DIM;
            int y = u >> 8, k = u & 255;           // W2t[y][k] = W2[k][y]
            W2t[u] = f2bf(W2[k * Y_DIM + y]);
        }
    } else {
        __shared__ int h[NB];
        int j = b - NORM_BLOCKS - CONV_BLOCKS;     // chunk id 0..195
        int t = threadIdx.x;
        for (int i = t; i < NB; i += 256) h[i] = 0;
        __syncthreads();
        int base = j * CHUNK;
        #pragma unroll
        for (int k = 0; k < CHUNK / 256; k++) {
            int e = base + t + k * 256;
            if (e < N_EDGES) atomicAdd(&h[rows[e] >> BUCKET_SHIFT], 1);
        }
        __syncthreads();
        for (int i = t; i < NB; i += 256) gpartial[j * NB + i] = h[i];
    }
}

// ---------------------------------------------------------------------------
// Bucket scan (1 block): totals = sum_j gpartial[j][b]; exclusive scan ->
// bucket_base (392 entries) + bcursor seed; rp4 sentinel.
// ---------------------------------------------------------------------------
__global__ __launch_bounds__(512) void bucket_scan_kernel(
    const int* __restrict__ gpartial, int* __restrict__ bucket_base,
    int* __restrict__ bcursor, int* __restrict__ rp4) {
    __shared__ int s[512];
    int t = threadIdx.x;
    int total = 0;
    if (t < NB) {
        #pragma unroll 4
        for (int j = 0; j < NCHUNK; j++) total += gpartial[j * NB + t];
    }
    s[t] = total;
    __syncthreads();
    #pragma unroll
    for (int off = 1; off < 512; off <<= 1) {
        int u = (t >= off) ? s[t - off] : 0;
        __syncthreads();
        s[t] += u;
        __syncthreads();
    }
    if (t < NB) {
        int excl = s[t] - total;
        bucket_base[t] = excl;
        bcursor[t] = excl;
    }
    if (t == 0) { bucket_base[NB] = N_EDGES; rp4[NB * 512] = N_EDGES; }
}

// ---------------------------------------------------------------------------
// Bucketize: compact each 4096-edge chunk into per-bucket LDS runs (offsets
// from gpartial), reserve global ranges via one atomic per bucket, copy out.
// Edge payload: word0 = col(16) | lrow(7) | bucket(9), word1 = fp32 val.
// ---------------------------------------------------------------------------
__global__ __launch_bounds__(512) void bucketize_kernel(
    const int* __restrict__ rows, const int* __restrict__ cols,
    const float* __restrict__ vals, const int* __restrict__ gpartial,
    int* __restrict__ bcursor, int2* __restrict__ edges) {
    __shared__ int ob[512];            // exclusive chunk-local bucket offsets
    __shared__ int c[NB];              // placement cursors
    __shared__ int g[NB];              // reserved global bases
    __shared__ int2 buf[CHUNK];        // 32 KB
    int t = threadIdx.x;
    int j = blockIdx.x;
    int base = j * CHUNK;
    int M = N_EDGES - base; if (M > CHUNK) M = CHUNK;
    int cnt = (t < NB) ? gpartial[j * NB + t] : 0;
    ob[t] = cnt;
    __syncthreads();
    #pragma unroll
    for (int off = 1; off < 512; off <<= 1) {
        int u = (t >= off) ? ob[t - off] : 0;
        __syncthreads();
        ob[t] += u;
        __syncthreads();
    }
    ob[t] -= cnt;  // exclusive (own slot only)
    if (t < NB) {
        c[t] = 0;
        g[t] = (cnt > 0) ? atomicAdd(&bcursor[t], cnt) : 0;
    }
    __syncthreads();
    #pragma unroll
    for (int k = 0; k < CHUNK / 512; k++) {
        int e = base + t + k * 512;
        if (e < N_EDGES) {
            int r = rows[e];
            int bb = r >> BUCKET_SHIFT;
            int p = ob[bb] + atomicAdd(&c[bb], 1);
            buf[p] = make_int2(cols[e] | ((r & 127) << 16) | (bb << 23),
                               __float_as_int(vals[e]));
        }
    }
    __syncthreads();
    for (int i = t; i < M; i += 512) {
        int2 e = buf[i];
        int bb = (int)((uint32)e.x >> 23);
        edges[g[bb] + (i - ob[bb])] = e;
    }
}

// ---------------------------------------------------------------------------
// Bucket sort: per-bucket LDS counting sort by key (panel, localrow) -> 512
// keys; emits rp4[bucket*512 + panel*128 + lrow] = global segment start.
// Global-scratch fallback if bucket > CAP_B.
// ---------------------------------------------------------------------------
__global__ __launch_bounds__(512) void bucket_sort_kernel(
    const int* __restrict__ bucket_base, int2* __restrict__ edges,
    int2* __restrict__ scratch, int* __restrict__ rp4) {
    __shared__ int2 buf[CAP_B];   // 20.5 KB
    __shared__ int2 buf2[CAP_B];  // 20.5 KB
    __shared__ int h[512], o[512], c[512];
    int b = blockIdx.x, t = threadIdx.x;
    int base = bucket_base[b];
    int cnt = bucket_base[b + 1] - base;
    bool fits = (cnt <= CAP_B);
    h[t] = 0;
    __syncthreads();
    for (int i = t; i < cnt; i += 512) {
        int2 e = edges[base + i];
        if (fits) buf[i] = e; else scratch[base + i] = e;
        int col = e.x & 0xFFFF;
        int key = (panel_of(col) << 7) + ((e.x >> 16) & 127);
        atomicAdd(&h[key], 1);
    }
    __syncthreads();
    int valh = h[t];
    #pragma unroll
    for (int off = 1; off < 512; off <<= 1) {
        int u = (t >= off) ? h[t - off] : 0;
        __syncthreads();
        h[t] += u;
        __syncthreads();
    }
    int excl = h[t] - valh;
    o[t] = excl;
    c[t] = 0;
    rp4[(b << 9) + t] = base + excl;
    __syncthreads();
    for (int i = t; i < cnt; i += 512) {
        int2 e = fits ? buf[i] : scratch[base + i];
        int col = e.x & 0xFFFF;
        int key = (panel_of(col) << 7) + ((e.x >> 16) & 127);
        int p = o[key] + atomicAdd(&c[key], 1);
        if (fits) buf2[p] = e; else edges[base + p] = e;
    }
    __syncthreads();
    if (fits)
        for (int i = t; i < cnt; i += 512) edges[base + i] = buf2[i];
}

// ---------------------------------------------------------------------------
// Dual-row segment accumulator: lanes 0-31 process row A (lane owns dims
// hl*4..hl*4+3 via uint2 = 4 bf16), lanes 32-63 row B. 4-wide edge unroll
// (panel segments average ~4 edges). Accumulates into A0..A3 (caller owns
// init), so it can be called once per panel. Edge loads are non-temporal
// (read-once stream) so they don't evict the L2-resident feature panel.
// ---------------------------------------------------------------------------
__device__ __forceinline__ void spmm_seg2(const uint2* __restrict__ feat2,
                                          const int2* __restrict__ edges,
                                          int start, int end, int lane,
                                          float& A0, float& A1, float& A2, float& A3) {
    const int hl = lane & 31;
    const int bsrc = lane & 32;   // shfl source base for my half
    int cur = start;
    while (__any(cur < end)) {
        int n = end - cur;
        n = n < 0 ? 0 : (n > 32 ? 32 : n);
        unsigned long long evu = 0;
        if (hl < n)
            evu = __builtin_nontemporal_load(
                (const unsigned long long*)(edges + cur + hl));
        int c = (int)(evu & 0xFFFFull);
        float v = __uint_as_float((uint32)(evu >> 32));
        int na = __shfl(n, 0, 64), nb = __shfl(n, 32, 64);
        int nm = na > nb ? na : nb;
        int jm = (nm + 3) & ~3;
        for (int j = 0; j < jm; j += 4) {
            int c0 = __shfl(c, bsrc + j, 64),     c1 = __shfl(c, bsrc + j + 1, 64);
            int c2 = __shfl(c, bsrc + j + 2, 64), c3 = __shfl(c, bsrc + j + 3, 64);
            float v0 = __shfl(v, bsrc + j, 64),     v1 = __shfl(v, bsrc + j + 1, 64);
            float v2 = __shfl(v, bsrc + j + 2, 64), v3 = __shfl(v, bsrc + j + 3, 64);
            uint2 f0 = feat2[(size_t)c0 * 32 + hl];
            uint2 f1 = feat2[(size_t)c1 * 32 + hl];
            uint2 f2 = feat2[(size_t)c2 * 32 + hl];
            uint2 f3 = feat2[(size_t)c3 * 32 + hl];
            A0 += v0 * bf_lo(f0.x); A1 += v0 * bf_hi(f0.x);
            A2 += v0 * bf_lo(f0.y); A3 += v0 * bf_hi(f0.y);
            A0 += v1 * bf_lo(f1.x); A1 += v1 * bf_hi(f1.x);
            A2 += v1 * bf_lo(f1.y); A3 += v1 * bf_hi(f1.y);
            A0 += v2 * bf_lo(f2.x); A1 += v2 * bf_hi(f2.x);
            A2 += v2 * bf_lo(f2.y); A3 += v2 * bf_hi(f2.y);
            A0 += v3 * bf_lo(f3.x); A1 += v3 * bf_hi(f3.x);
            A2 += v3 * bf_lo(f3.y); A3 += v3 * bf_hi(f3.y);
        }
        cur += n;
    }
}

// ---------------------------------------------------------------------------
// Fused SPMM + double GEMM per 64-row tile (512 thr, 8 waves):
//   phase 0: panel-outer gather. Each wave owns 8 rows (4 dual-row pairs);
//            all 16 accumulators stay live so all waves sweep panel p of
//            xb together (L2-resident 3.2 MB slice) before moving to p+1.
//   phase 1: h = relu(A @ W1 + b1) via MFMA, wave owns 32 h-cols.
//   phase 2: hw = h @ W2, wave owns 16 hw-cols. Written bf16 (non-temporal).
// LDS 51.2 KB -> 3 blocks/CU; launch_bounds(512,6) caps VGPR at ~84 so the
// 24-wave occupancy is register-feasible.
// ---------------------------------------------------------------------------
__global__ __launch_bounds__(512, 6) void spmm_gemm_fused(
    const uint32* __restrict__ xb, const int* __restrict__ rp4,
    const int2* __restrict__ edges, const ushort16* __restrict__ W1t,
    const ushort16* __restrict__ W2t, const float* __restrict__ b1,
    ushort16* __restrict__ hw) {
    __shared__ ushort16 a_s[64 * 136];  // 17.4 KB
    __shared__ ushort16 h_s[64 * 264];  // 33.8 KB
    const int tx = threadIdx.x;
    const int wave = tx >> 6, lane = tx & 63;
    const int quad = lane >> 4, l16 = lane & 15;
    const int half = lane >> 5, hl = lane & 31;
    const int row0 = blockIdx.x * 64;
    const int bkt = row0 >> 7;
    const uint2* xb2 = (const uint2*)xb;

    // Phase 0: panel-outer gather of 8 rows per wave into the A-tile
    float ac[4][4];
    #pragma unroll
    for (int i = 0; i < 4; i++)
        #pragma unroll
        for (int d = 0; d < 4; d++) ac[i][d] = 0.f;
    for (int p = 0; p < 4; p++) {
        #pragma unroll
        for (int i = 0; i < 4; i++) {
            int row = row0 + wave * 8 + i * 2 + half;
            int s = 0, e = 0;
            if (row < N_NODES) {
                int idx = (bkt << 9) + (p << 7) + (row & 127);
                s = rp4[idx];
                e = rp4[idx + 1];
            }
            spmm_seg2(xb2, edges, s, e, lane, ac[i][0], ac[i][1], ac[i][2], ac[i][3]);
        }
    }
    #pragma unroll
    for (int i = 0; i < 4; i++) {
        int r = wave * 8 + i * 2 + half;
        uint32 lo = (uint32)f2bf(ac[i][0]) | ((uint32)f2bf(ac[i][1]) << 16);
        uint32 hi = (uint32)f2bf(ac[i][2]) | ((uint32)f2bf(ac[i][3]) << 16);
        *(uint2*)&a_s[r * 136 + hl * 4] = make_uint2(lo, hi);
    }

    // Preload stage-1 B fragments AFTER the gather (register pressure):
    // wave owns h-cols [wave*32, wave*32+32)
    short8 bfr1[2][4];  // [ct][kk]
    #pragma unroll
    for (int ct = 0; ct < 2; ct++)
        #pragma unroll
        for (int kk = 0; kk < 4; kk++)
            bfr1[ct][kk] = *(const short8*)
                &W1t[(wave * 32 + ct * 16 + l16) * 128 + kk * 32 + quad * 8];
    __syncthreads();

    // Phase 1: h = relu(A @ W1 + b1)
    floatx4 acc1[4][2];  // [rs][ct]
    #pragma unroll
    for (int rs = 0; rs < 4; rs++)
        #pragma unroll
        for (int ct = 0; ct < 2; ct++)
            #pragma unroll
            for (int j = 0; j < 4; j++) acc1[rs][ct][j] = 0.f;
    #pragma unroll
    for (int kk = 0; kk < 4; kk++) {
        #pragma unroll
        for (int rs = 0; rs < 4; rs++) {
            short8 af = *(const short8*)&a_s[(rs * 16 + l16) * 136 + kk * 32 + quad * 8];
            #pragma unroll
            for (int ct = 0; ct < 2; ct++)
                acc1[rs][ct] = __builtin_amdgcn_mfma_f32_16x16x32_bf16(
                    af, bfr1[ct][kk], acc1[rs][ct], 0, 0, 0);
        }
    }
    float bv[2];
    #pragma unroll
    for (int ct = 0; ct < 2; ct++) bv[ct] = b1[wave * 32 + ct * 16 + l16];
    #pragma unroll
    for (int rs = 0; rs < 4; rs++)
        #pragma unroll
        for (int ct = 0; ct < 2; ct++)
            #pragma unroll
            for (int reg = 0; reg < 4; reg++) {
                float v = acc1[rs][ct][reg] + bv[ct];
                v = v > 0.f ? v : 0.f;
                h_s[(rs * 16 + quad * 4 + reg) * 264 + wave * 32 + ct * 16 + l16] = f2bf(v);
            }

    // Preload stage-2 B fragments: wave owns hw-cols [wave*16, wave*16+16)
    short8 bfr2[8];
    #pragma unroll
    for (int kk = 0; kk < 8; kk++)
        bfr2[kk] = *(const short8*)
            &W2t[(wave * 16 + l16) * 256 + kk * 32 + quad * 8];
    __syncthreads();

    // Phase 2: hw = h @ W2
    floatx4 acc2[4];
    #pragma unroll
    for (int rs = 0; rs < 4; rs++)
        #pragma unroll
        for (int j = 0; j < 4; j++) acc2[rs][j] = 0.f;
    #pragma unroll
    for (int kk = 0; kk < 8; kk++) {
        #pragma unroll
        for (int rs = 0; rs < 4; rs++) {
            short8 af = *(const short8*)&h_s[(rs * 16 + l16) * 264 + kk * 32 + quad * 8];
            acc2[rs] = __builtin_amdgcn_mfma_f32_16x16x32_bf16(
                af, bfr2[kk], acc2[rs], 0, 0, 0);
        }
    }
    #pragma unroll
    for (int rs = 0; rs < 4; rs++)
        #pragma unroll
        for (int reg = 0; reg < 4; reg++) {
            int row = row0 + rs * 16 + quad * 4 + reg;
            if (row < N_NODES)
                __builtin_nontemporal_store(
                    f2bf(acc2[rs][reg]),
                    &hw[(size_t)row * 128 + wave * 16 + l16]);
        }
}

// ---------------------------------------------------------------------------
// Final spmm: out = A @ hw + b2 (fp32 out, non-temporal). Same shape as the
// fused gather phase: 782 blocks x 8 waves x 8 rows, panel-outer, so the
// whole grid is co-resident and walks hw's panels in lockstep (L2-hit).
// ---------------------------------------------------------------------------
__global__ __launch_bounds__(512, 6) void spmm_out_kernel(
    const uint32* __restrict__ feat, const int* __restrict__ rp4,
    const int2* __restrict__ edges, const float* __restrict__ bias,
    float* __restrict__ out) {
    const int tx = threadIdx.x;
    const int wave = tx >> 6, lane = tx & 63;
    const int half = lane >> 5, hl = lane & 31;
    const int row0 = blockIdx.x * 64;
    const int bkt = row0 >> 7;
    const uint2* f2 = (const uint2*)feat;

    float ac[4][4];
    #pragma unroll
    for (int i = 0; i < 4; i++)
        #pragma unroll
        for (int d = 0; d < 4; d++) ac[i][d] = 0.f;
    for (int p = 0; p < 4; p++) {
        #pragma unroll
        for (int i = 0; i < 4; i++) {
            int row = row0 + wave * 8 + i * 2 + half;
            int s = 0, e = 0;
            if (row < N_NODES) {
                int idx = (bkt << 9) + (p << 7) + (row & 127);
                s = rp4[idx];
                e = rp4[idx + 1];
            }
            spmm_seg2(f2, edges, s, e, lane, ac[i][0], ac[i][1], ac[i][2], ac[i][3]);
        }
    }
    float4 bv = ((const float4*)bias)[hl];
    #pragma unroll
    for (int i = 0; i < 4; i++) {
        int row = row0 + wave * 8 + i * 2 + half;
        if (row < N_NODES) {
            floatx4 o4;
            o4[0] = ac[i][0] + bv.x;
            o4[1] = ac[i][1] + bv.y;
            o4[2] = ac[i][2] + bv.z;
            o4[3] = ac[i][3] + bv.w;
            __builtin_nontemporal_store(o4, (floatx4*)out + (size_t)row * 32 + hl);
        }
    }
}

extern "C" void kernel_launch(void* const* d_in, const int* in_sizes, int n_in,
                              void* d_out, int out_size, void* d_ws, size_t ws_size,
                              hipStream_t stream) {
    const float* x = (const float*)d_in[0];
    const float* adj_vals = (const float*)d_in[1];
    const int* adj_row = (const int*)d_in[2];
    const int* adj_col = (const int*)d_in[3];
    const float* W1 = (const float*)d_in[4];
    const float* b1 = (const float*)d_in[5];
    const float* W2 = (const float*)d_in[6];
    const float* b2 = (const float*)d_in[7];
    float* out = (float*)d_out;

    // Workspace layout (~39.7 MB):
    char* ws = (char*)d_ws;
    uint32*   xb       = (uint32*)  (ws + 0);            // 12.8 MB (bf16 x-norm)
    ushort16* hw       = (ushort16*)(ws + 12800000);     // 12.8 MB (bf16)
    int2*     edges    = (int2*)    (ws + 25600000);     //  6.4 MB
    int2*     scratch  = (int2*)    (ws + 32000000);     //  6.4 MB (fallback only)
    int*      gpartial = (int*)     (ws + 38400000);     //  306 KB
    int*      rp4      = (int*)     (ws + 38707200);     //  801 KB (391*512+1 ints)
    int*      bbase    = (int*)     (ws + 39508480);     //  1.6 KB
    int*      bcursor  = (int*)     (ws + 39510528);     //  1.6 KB
    ushort16* W1t      = (ushort16*)(ws + 39512576);     //   64 KB
    ushort16* W2t      = (ushort16*)(ws + 39578112);     //   64 KB

    // 1. prep: x-hat bf16 + transposed bf16 weights + per-chunk bucket hists
    hipLaunchKernelGGL(prep_kernel, dim3(NORM_BLOCKS + CONV_BLOCKS + NCHUNK),
                       dim3(256), 0, stream, x, xb, W1, W2, W1t, W2t,
                       adj_row, gpartial);

    // 2. bucket bases (scan of 391 totals)
    hipLaunchKernelGGL(bucket_scan_kernel, dim3(1), dim3(512),
                       0, stream, gpartial, bbase, bcursor, rp4);

    // 3. bucketize (coalesced) + per-bucket (panel,lrow) sort (emits rp4)
    hipLaunchKernelGGL(bucketize_kernel, dim3(NCHUNK), dim3(512),
                       0, stream, adj_row, adj_col, adj_vals, gpartial, bcursor, edges);
    hipLaunchKernelGGL(bucket_sort_kernel, dim3(NB), dim3(512),
                       0, stream, bbase, edges, scratch, rp4);

    // 4. hw = relu((A @ x-hat) @ W1 + b1) @ W2   [fused spmm + MFMA GEMMs]
    hipLaunchKernelGGL(spmm_gemm_fused, dim3((N_NODES + 63) / 64), dim3(512),
                       0, stream, xb, rp4, edges, W1t, W2t, b1, hw);

    // 5. out = A @ hw + b2
    hipLaunchKernelGGL(spmm_out_kernel, dim3((N_NODES + 63) / 64), dim3(512),
                       0, stream, (const uint32*)hw, rp4, edges, b2, out);
}

// Round 2
// 223.971 us; speedup vs baseline: 1.1352x; 1.1352x over previous
//
#include <hip/hip_runtime.h>

// Problem constants (fixed by the reference).
#define N_NODES 50000
#define N_EDGES 800000
#define X_DIM 128
#define H_DIM 256
#define Y_DIM 128

typedef unsigned int uint32;
typedef unsigned short ushort16;
typedef __attribute__((ext_vector_type(8))) short short8;
typedef __attribute__((ext_vector_type(4))) float floatx4;

// bf16 helpers (round-to-nearest-even)
__device__ inline ushort16 f2bf(float f) {
    uint32 u = __float_as_uint(f);
    return (ushort16)((u + 0x7FFFu + ((u >> 16) & 1u)) >> 16);
}
__device__ inline float bf_lo(uint32 u) { return __uint_as_float(u << 16); }
__device__ inline float bf_hi(uint32 u) { return __uint_as_float(u & 0xFFFF0000u); }

// Bucket geometry: 391 buckets of 128 rows; 196 chunks of 4096 edges.
#define BUCKET_SHIFT 7
#define NB 391              // ceil(50000/128)
#define CHUNK 4096
#define NCHUNK 196          // ceil(800000/4096)
#define CAP_B 2560          // LDS capacity per bucket (mean 2046)

#define NORM_BLOCKS 12500   // N_NODES*64/256
#define CONV_BLOCKS 256     // 65536/256

// ---------------------------------------------------------------------------
// Prep (fused): row-normalize x -> bf16; transpose-convert W1,W2 to bf16;
// per-chunk bucket histograms -> gpartial[chunk][bucket] (no global atomics).
// ---------------------------------------------------------------------------
__global__ __launch_bounds__(256) void prep_kernel(
    const float* __restrict__ x, uint32* __restrict__ xb,
    const float* __restrict__ W1, const float* __restrict__ W2,
    ushort16* __restrict__ W1t, ushort16* __restrict__ W2t,
    const int* __restrict__ rows, int* __restrict__ gpartial) {
    int b = blockIdx.x;
    if (b < NORM_BLOCKS) {
        int row = (b * 256 + threadIdx.x) >> 6;  // exact: 12500*4 = 50000 rows
        int lane = threadIdx.x & 63;
        float2 v = ((const float2*)x)[(size_t)row * 64 + lane];
        float s = v.x + v.y;
        #pragma unroll
        for (int off = 32; off > 0; off >>= 1) s += __shfl_xor(s, off, 64);
        float inv = 1.0f / (s + 1e-4f);
        uint32 lo = (uint32)f2bf(v.x * inv);
        uint32 hi = (uint32)f2bf(v.y * inv);
        xb[(size_t)row * 64 + lane] = lo | (hi << 16);
    } else if (b < NORM_BLOCKS + CONV_BLOCKS) {
        int t = (b - NORM_BLOCKS) * 256 + threadIdx.x;  // 0..65535
        if (t < X_DIM * H_DIM) {
            int n = t >> 7, k = t & 127;           // W1t[n][k] = W1[k][n]
            W1t[t] = f2bf(W1[k * H_DIM + n]);
        } else {
            int u = t - X_DIM * H_DIM;
            int y = u >> 8, k = u & 255;           // W2t[y][k] = W2[k][y]
            W2t[u] = f2bf(W2[k * Y_DIM + y]);
        }
    } else {
        __shared__ int h[NB];
        int j = b - NORM_BLOCKS - CONV_BLOCKS;     // chunk id 0..195
        int t = threadIdx.x;
        for (int i = t; i < NB; i += 256) h[i] = 0;
        __syncthreads();
        int base = j * CHUNK;
        #pragma unroll
        for (int k = 0; k < CHUNK / 256; k++) {
            int e = base + t + k * 256;
            if (e < N_EDGES) atomicAdd(&h[rows[e] >> BUCKET_SHIFT], 1);
        }
        __syncthreads();
        for (int i = t; i < NB; i += 256) gpartial[j * NB + i] = h[i];
    }
}

// ---------------------------------------------------------------------------
// Bucket scan (1 block): totals = sum_j gpartial[j][b]; exclusive scan ->
// bucket_base (392 entries) + bcursor seed; rowptr[N] = E.
// ---------------------------------------------------------------------------
__global__ __launch_bounds__(512) void bucket_scan_kernel(
    const int* __restrict__ gpartial, int* __restrict__ bucket_base,
    int* __restrict__ bcursor, int* __restrict__ rowptr) {
    __shared__ int s[512];
    int t = threadIdx.x;
    int total = 0;
    if (t < NB) {
        #pragma unroll 4
        for (int j = 0; j < NCHUNK; j++) total += gpartial[j * NB + t];
    }
    s[t] = total;
    __syncthreads();
    #pragma unroll
    for (int off = 1; off < 512; off <<= 1) {
        int u = (t >= off) ? s[t - off] : 0;
        __syncthreads();
        s[t] += u;
        __syncthreads();
    }
    if (t < NB) {
        int excl = s[t] - total;
        bucket_base[t] = excl;
        bcursor[t] = excl;
    }
    if (t == 0) { bucket_base[NB] = N_EDGES; rowptr[N_NODES] = N_EDGES; }
}

// ---------------------------------------------------------------------------
// Bucketize: compact each 4096-edge chunk into per-bucket LDS runs (offsets
// from gpartial), reserve global ranges via one atomic per bucket, copy out.
// Edge payload: word0 = col(16) | lrow(7) | bucket(9), word1 = fp32 val.
// ---------------------------------------------------------------------------
__global__ __launch_bounds__(512) void bucketize_kernel(
    const int* __restrict__ rows, const int* __restrict__ cols,
    const float* __restrict__ vals, const int* __restrict__ gpartial,
    int* __restrict__ bcursor, int2* __restrict__ edges) {
    __shared__ int ob[512];            // exclusive chunk-local bucket offsets
    __shared__ int c[NB];              // placement cursors
    __shared__ int g[NB];              // reserved global bases
    __shared__ int2 buf[CHUNK];        // 32 KB
    int t = threadIdx.x;
    int j = blockIdx.x;
    int base = j * CHUNK;
    int M = N_EDGES - base; if (M > CHUNK) M = CHUNK;
    int cnt = (t < NB) ? gpartial[j * NB + t] : 0;
    ob[t] = cnt;
    __syncthreads();
    #pragma unroll
    for (int off = 1; off < 512; off <<= 1) {
        int u = (t >= off) ? ob[t - off] : 0;
        __syncthreads();
        ob[t] += u;
        __syncthreads();
    }
    ob[t] -= cnt;  // exclusive (own slot only)
    if (t < NB) {
        c[t] = 0;
        g[t] = (cnt > 0) ? atomicAdd(&bcursor[t], cnt) : 0;
    }
    __syncthreads();
    #pragma unroll
    for (int k = 0; k < CHUNK / 512; k++) {
        int e = base + t + k * 512;
        if (e < N_EDGES) {
            int r = rows[e];
            int bb = r >> BUCKET_SHIFT;
            int p = ob[bb] + atomicAdd(&c[bb], 1);
            buf[p] = make_int2(cols[e] | ((r & 127) << 16) | (bb << 23),
                               __float_as_int(vals[e]));
        }
    }
    __syncthreads();
    for (int i = t; i < M; i += 512) {
        int2 e = buf[i];
        int bb = (int)((uint32)e.x >> 23);
        edges[g[bb] + (i - ob[bb])] = e;
    }
}

// ---------------------------------------------------------------------------
// Bucket sort: per-bucket LDS counting sort by local row, in place; ALSO
// emits rowptr for its 128 rows. Global-scratch fallback if bucket > CAP_B.
// ---------------------------------------------------------------------------
__global__ __launch_bounds__(256) void bucket_sort_kernel(
    const int* __restrict__ bucket_base, int2* __restrict__ edges,
    int2* __restrict__ scratch, int* __restrict__ rowptr) {
    __shared__ int2 buf[CAP_B];   // 20.5 KB
    __shared__ int2 buf2[CAP_B];  // 20.5 KB
    __shared__ int h[128], o[128], c[128];
    int b = blockIdx.x, t = threadIdx.x;
    int base = bucket_base[b];
    int cnt = bucket_base[b + 1] - base;
    bool fits = (cnt <= CAP_B);
    if (t < 128) h[t] = 0;
    __syncthreads();
    for (int i = t; i < cnt; i += 256) {
        int2 e = edges[base + i];
        if (fits) buf[i] = e; else scratch[base + i] = e;
        atomicAdd(&h[(e.x >> 16) & 127], 1);
    }
    __syncthreads();
    int valh = (t < 128) ? h[t] : 0;
    #pragma unroll
    for (int off = 1; off < 128; off <<= 1) {
        int u = (t >= off && t < 128) ? h[t - off] : 0;
        __syncthreads();
        if (t < 128) h[t] += u;
        __syncthreads();
    }
    if (t < 128) {
        o[t] = h[t] - valh;
        c[t] = 0;
        int i = (b << BUCKET_SHIFT) + t;
        if (i < N_NODES) rowptr[i] = base + h[t] - valh;
    }
    __syncthreads();
    for (int i = t; i < cnt; i += 256) {
        int2 e = fits ? buf[i] : scratch[base + i];
        int lr = (e.x >> 16) & 127;
        int p = o[lr] + atomicAdd(&c[lr], 1);
        if (fits) buf2[p] = e; else edges[base + p] = e;
    }
    __syncthreads();
    if (fits)
        for (int i = t; i < cnt; i += 256) edges[base + i] = buf2[i];
}

// ---------------------------------------------------------------------------
// Dual-row spmm accumulator: lanes 0-31 process row A (lane owns dims
// hl*4..hl*4+3 via uint2 = 4 bf16), lanes 32-63 row B. 16-wide edge unroll:
// 16 independent 8B gathers in flight serving two rows at once (MLP is the
// binding constraint: ~500-900cy L3/HBM latency on random gathers).
// start/end are per-lane (uniform within each half).
// ---------------------------------------------------------------------------
__device__ __forceinline__ void spmm_row2(const uint2* __restrict__ feat2,
                                          const int2* __restrict__ edges,
                                          int start, int end, int lane,
                                          float& A0, float& A1, float& A2, float& A3) {
    const int hl = lane & 31;
    const int bsrc = lane & 32;   // shfl source base for my half
    float x0 = 0.f, x1 = 0.f, x2 = 0.f, x3 = 0.f;
    int cur = start;
    while (__any(cur < end)) {
        int n = end - cur;
        n = n < 0 ? 0 : (n > 32 ? 32 : n);
        int2 ev = make_int2(0, 0);
        if (hl < n) ev = edges[cur + hl];
        int c = ev.x & 0xFFFF;
        float v = __int_as_float(ev.y);
        int na = __shfl(n, 0, 64), nb = __shfl(n, 32, 64);
        int nm = na > nb ? na : nb;
        int jm = (nm + 15) & ~15;
        for (int j = 0; j < jm; j += 16) {
            uint2 f[16];
            float vv[16];
            #pragma unroll
            for (int u = 0; u < 16; u++) {
                int cc = __shfl(c, bsrc + j + u, 64);
                vv[u] = __shfl(v, bsrc + j + u, 64);
                f[u] = feat2[(size_t)cc * 32 + hl];
            }
            #pragma unroll
            for (int u = 0; u < 16; u++) {
                x0 += vv[u] * bf_lo(f[u].x); x1 += vv[u] * bf_hi(f[u].x);
                x2 += vv[u] * bf_lo(f[u].y); x3 += vv[u] * bf_hi(f[u].y);
            }
        }
        cur += n;
    }
    A0 = x0; A1 = x1; A2 = x2; A3 = x3;
}

// ---------------------------------------------------------------------------
// Fused SPMM + double GEMM per 64-row tile (512 thr, 8 waves):
//   phase 0: each wave gathers 8 rows (4 passes x 2 rows, dual-row) of
//            agg1 = A @ x-hat straight into the LDS A-tile (packed bf16).
//   phase 1: h = relu(A @ W1 + b1) via MFMA, wave owns 32 h-cols
//            (B-fragments loaded AFTER phase 0 to free gather registers).
//   phase 2: hw = h @ W2, wave owns 16 hw-cols. Written bf16.
// LDS 51.2 KB -> 3 blocks/CU (24 waves); VGPR budget 128 (launch_bounds 4).
// ---------------------------------------------------------------------------
__global__ __launch_bounds__(512, 4) void spmm_gemm_fused(
    const uint32* __restrict__ xb, const int* __restrict__ rowptr,
    const int2* __restrict__ edges, const ushort16* __restrict__ W1t,
    const ushort16* __restrict__ W2t, const float* __restrict__ b1,
    ushort16* __restrict__ hw) {
    __shared__ ushort16 a_s[64 * 136];  // 17.4 KB
    __shared__ ushort16 h_s[64 * 264];  // 33.8 KB
    const int tx = threadIdx.x;
    const int wave = tx >> 6, lane = tx & 63;
    const int quad = lane >> 4, l16 = lane & 15;
    const int half = lane >> 5, hl = lane & 31;
    const int row0 = blockIdx.x * 64;
    const uint2* xb2 = (const uint2*)xb;

    // Phase 0: gather 8 rows per wave (2 at a time) into the A-tile
    for (int i = 0; i < 4; i++) {
        int r = wave * 8 + i * 2 + half;
        int row = row0 + r;
        int s = 0, e = 0;
        if (row < N_NODES) { s = rowptr[row]; e = rowptr[row + 1]; }
        float a0, a1, a2, a3;
        spmm_row2(xb2, edges, s, e, lane, a0, a1, a2, a3);
        uint32 lo = (uint32)f2bf(a0) | ((uint32)f2bf(a1) << 16);
        uint32 hi = (uint32)f2bf(a2) | ((uint32)f2bf(a3) << 16);
        *(uint2*)&a_s[r * 136 + hl * 4] = make_uint2(lo, hi);
    }

    // Preload stage-1 B fragments AFTER the gather (register pressure):
    // wave owns h-cols [wave*32, wave*32+32)
    short8 bfr1[2][4];  // [ct][kk]
    #pragma unroll
    for (int ct = 0; ct < 2; ct++)
        #pragma unroll
        for (int kk = 0; kk < 4; kk++)
            bfr1[ct][kk] = *(const short8*)
                &W1t[(wave * 32 + ct * 16 + l16) * 128 + kk * 32 + quad * 8];
    __syncthreads();

    // Phase 1: h = relu(A @ W1 + b1)
    floatx4 acc1[4][2];  // [rs][ct]
    #pragma unroll
    for (int rs = 0; rs < 4; rs++)
        #pragma unroll
        for (int ct = 0; ct < 2; ct++)
            #pragma unroll
            for (int j = 0; j < 4; j++) acc1[rs][ct][j] = 0.f;
    #pragma unroll
    for (int kk = 0; kk < 4; kk++) {
        #pragma unroll
        for (int rs = 0; rs < 4; rs++) {
            short8 af = *(const short8*)&a_s[(rs * 16 + l16) * 136 + kk * 32 + quad * 8];
            #pragma unroll
            for (int ct = 0; ct < 2; ct++)
                acc1[rs][ct] = __builtin_amdgcn_mfma_f32_16x16x32_bf16(
                    af, bfr1[ct][kk], acc1[rs][ct], 0, 0, 0);
        }
    }
    float bv[2];
    #pragma unroll
    for (int ct = 0; ct < 2; ct++) bv[ct] = b1[wave * 32 + ct * 16 + l16];
    #pragma unroll
    for (int rs = 0; rs < 4; rs++)
        #pragma unroll
        for (int ct = 0; ct < 2; ct++)
            #pragma unroll
            for (int reg = 0; reg < 4; reg++) {
                float v = acc1[rs][ct][reg] + bv[ct];
                v = v > 0.f ? v : 0.f;
                h_s[(rs * 16 + quad * 4 + reg) * 264 + wave * 32 + ct * 16 + l16] = f2bf(v);
            }

    // Preload stage-2 B fragments: wave owns hw-cols [wave*16, wave*16+16)
    short8 bfr2[8];
    #pragma unroll
    for (int kk = 0; kk < 8; kk++)
        bfr2[kk] = *(const short8*)
            &W2t[(wave * 16 + l16) * 256 + kk * 32 + quad * 8];
    __syncthreads();

    // Phase 2: hw = h @ W2
    floatx4 acc2[4];
    #pragma unroll
    for (int rs = 0; rs < 4; rs++)
        #pragma unroll
        for (int j = 0; j < 4; j++) acc2[rs][j] = 0.f;
    #pragma unroll
    for (int kk = 0; kk < 8; kk++) {
        #pragma unroll
        for (int rs = 0; rs < 4; rs++) {
            short8 af = *(const short8*)&h_s[(rs * 16 + l16) * 264 + kk * 32 + quad * 8];
            acc2[rs] = __builtin_amdgcn_mfma_f32_16x16x32_bf16(
                af, bfr2[kk], acc2[rs], 0, 0, 0);
        }
    }
    #pragma unroll
    for (int rs = 0; rs < 4; rs++)
        #pragma unroll
        for (int reg = 0; reg < 4; reg++) {
            int row = row0 + rs * 16 + quad * 4 + reg;
            if (row < N_NODES)
                hw[(size_t)row * 128 + wave * 16 + l16] = f2bf(acc2[rs][reg]);
        }
}

// ---------------------------------------------------------------------------
// Final spmm: out = A @ hw + b2 (fp32 out). One wave per 2 rows (dual-row).
// Grid exact: 6250 blocks x 4 waves x 2 rows = 50000.
// ---------------------------------------------------------------------------
__global__ __launch_bounds__(256) void spmm_out_kernel(
    const uint32* __restrict__ feat, const int* __restrict__ rowptr,
    const int2* __restrict__ edges, const float* __restrict__ bias,
    float* __restrict__ out) {
    int w = (blockIdx.x * blockDim.x + threadIdx.x) >> 6;
    int lane = threadIdx.x & 63;
    int half = lane >> 5, hl = lane & 31;
    int row = w * 2 + half;  // always < N_NODES (exact grid)
    int s = rowptr[row], e = rowptr[row + 1];
    float a0, a1, a2, a3;
    spmm_row2((const uint2*)feat, edges, s, e, lane, a0, a1, a2, a3);
    float4 b = ((const float4*)bias)[hl];
    ((float4*)out)[(size_t)row * 32 + hl] =
        make_float4(a0 + b.x, a1 + b.y, a2 + b.z, a3 + b.w);
}

extern "C" void kernel_launch(void* const* d_in, const int* in_sizes, int n_in,
                              void* d_out, int out_size, void* d_ws, size_t ws_size,
                              hipStream_t stream) {
    const float* x = (const float*)d_in[0];
    const float* adj_vals = (const float*)d_in[1];
    const int* adj_row = (const int*)d_in[2];
    const int* adj_col = (const int*)d_in[3];
    const float* W1 = (const float*)d_in[4];
    const float* b1 = (const float*)d_in[5];
    const float* W2 = (const float*)d_in[6];
    const float* b2 = (const float*)d_in[7];
    float* out = (float*)d_out;

    // Workspace layout (~39 MB):
    char* ws = (char*)d_ws;
    uint32*   xb       = (uint32*)  (ws + 0);            // 12.8 MB (bf16 x-norm)
    ushort16* hw       = (ushort16*)(ws + 12800000);     // 12.8 MB (bf16)
    int2*     edges    = (int2*)    (ws + 25600000);     //  6.4 MB
    int2*     scratch  = (int2*)    (ws + 32000000);     //  6.4 MB (fallback only)
    int*      gpartial = (int*)     (ws + 38400000);     //  306 KB
    int*      rowptr   = (int*)     (ws + 38713344);     //  200 KB
    int*      bbase    = (int*)     (ws + 38914048);     //  1.6 KB
    int*      bcursor  = (int*)     (ws + 38916096);     //  1.6 KB
    ushort16* W1t      = (ushort16*)(ws + 38918144);     //   64 KB
    ushort16* W2t      = (ushort16*)(ws + 38983680);     //   64 KB

    // 1. prep: x-hat bf16 + transposed bf16 weights + per-chunk bucket hists
    hipLaunchKernelGGL(prep_kernel, dim3(NORM_BLOCKS + CONV_BLOCKS + NCHUNK),
                       dim3(256), 0, stream, x, xb, W1, W2, W1t, W2t,
                       adj_row, gpartial);

    // 2. bucket bases (scan of 391 totals)
    hipLaunchKernelGGL(bucket_scan_kernel, dim3(1), dim3(512),
                       0, stream, gpartial, bbase, bcursor, rowptr);

    // 3. bucketize (coalesced) + per-bucket sort (emits rowptr)
    hipLaunchKernelGGL(bucketize_kernel, dim3(NCHUNK), dim3(512),
                       0, stream, adj_row, adj_col, adj_vals, gpartial, bcursor, edges);
    hipLaunchKernelGGL(bucket_sort_kernel, dim3(NB), dim3(256),
                       0, stream, bbase, edges, scratch, rowptr);

    // 4. hw = relu((A @ x-hat) @ W1 + b1) @ W2   [fused spmm + MFMA GEMMs]
    hipLaunchKernelGGL(spmm_gemm_fused, dim3((N_NODES + 63) / 64), dim3(512),
                       0, stream, xb, rowptr, edges, W1t, W2t, b1, hw);

    // 5. out = A @ hw + b2
    hipLaunchKernelGGL(spmm_out_kernel, dim3(N_NODES / 8), dim3(256),
                       0, stream, (const uint32*)hw, rowptr, edges, b2, out);
}

// Round 3
// 222.525 us; speedup vs baseline: 1.1426x; 1.0065x over previous
//
#include <hip/hip_runtime.h>

// Problem constants (fixed by the reference).
#define N_NODES 50000
#define N_EDGES 800000
#define X_DIM 128
#define H_DIM 256
#define Y_DIM 128

typedef unsigned int uint32;
typedef unsigned short ushort16;
typedef __attribute__((ext_vector_type(8))) short short8;
typedef __attribute__((ext_vector_type(4))) float floatx4;

// bf16 helpers (round-to-nearest-even)
__device__ inline ushort16 f2bf(float f) {
    uint32 u = __float_as_uint(f);
    return (ushort16)((u + 0x7FFFu + ((u >> 16) & 1u)) >> 16);
}
__device__ inline float bf_lo(uint32 u) { return __uint_as_float(u << 16); }
__device__ inline float bf_hi(uint32 u) { return __uint_as_float(u & 0xFFFF0000u); }

// Bucket geometry: 391 buckets of 128 rows; 196 chunks of 4096 edges.
#define BUCKET_SHIFT 7
#define NB 391              // ceil(50000/128)
#define CHUNK 4096
#define NCHUNK 196          // ceil(800000/4096)
#define CAP_B 2560          // LDS capacity per bucket in sort (mean 2046)
#define CAP_E 4224          // LDS capacity for a 64-row block's edges (mean 1024)

#define NORM_BLOCKS 12500   // N_NODES*64/256
#define CONV_BLOCKS 256     // 65536/256

// ---------------------------------------------------------------------------
// Prep (fused): row-normalize x -> bf16; transpose-convert W1,W2 to bf16;
// per-chunk bucket histograms -> gpartial[chunk][bucket] (no global atomics).
// ---------------------------------------------------------------------------
__global__ __launch_bounds__(256) void prep_kernel(
    const float* __restrict__ x, uint32* __restrict__ xb,
    const float* __restrict__ W1, const float* __restrict__ W2,
    ushort16* __restrict__ W1t, ushort16* __restrict__ W2t,
    const int* __restrict__ rows, int* __restrict__ gpartial) {
    int b = blockIdx.x;
    if (b < NORM_BLOCKS) {
        int row = (b * 256 + threadIdx.x) >> 6;  // exact: 12500*4 = 50000 rows
        int lane = threadIdx.x & 63;
        float2 v = ((const float2*)x)[(size_t)row * 64 + lane];
        float s = v.x + v.y;
        #pragma unroll
        for (int off = 32; off > 0; off >>= 1) s += __shfl_xor(s, off, 64);
        float inv = 1.0f / (s + 1e-4f);
        uint32 lo = (uint32)f2bf(v.x * inv);
        uint32 hi = (uint32)f2bf(v.y * inv);
        xb[(size_t)row * 64 + lane] = lo | (hi << 16);
    } else if (b < NORM_BLOCKS + CONV_BLOCKS) {
        int t = (b - NORM_BLOCKS) * 256 + threadIdx.x;  // 0..65535
        if (t < X_DIM * H_DIM) {
            int n = t >> 7, k = t & 127;           // W1t[n][k] = W1[k][n]
            W1t[t] = f2bf(W1[k * H_DIM + n]);
        } else {
            int u = t - X_DIM * H_DIM;
            int y = u >> 8, k = u & 255;           // W2t[y][k] = W2[k][y]
            W2t[u] = f2bf(W2[k * Y_DIM + y]);
        }
    } else {
        __shared__ int h[NB];
        int j = b - NORM_BLOCKS - CONV_BLOCKS;     // chunk id 0..195
        int t = threadIdx.x;
        for (int i = t; i < NB; i += 256) h[i] = 0;
        __syncthreads();
        int base = j * CHUNK;
        #pragma unroll
        for (int k = 0; k < CHUNK / 256; k++) {
            int e = base + t + k * 256;
            if (e < N_EDGES) atomicAdd(&h[rows[e] >> BUCKET_SHIFT], 1);
        }
        __syncthreads();
        for (int i = t; i < NB; i += 256) gpartial[j * NB + i] = h[i];
    }
}

// ---------------------------------------------------------------------------
// Bucketize (scan folded in): each of the 196 chunk-blocks redundantly
// reduces gpartial (306 KB, L2-hot) to get bucket totals + its own chunk
// prefix -> deterministic global write base, NO atomics, no scan kernel.
// Block 0 also emits bucket_base + sentinels. Then LDS-compact the chunk and
// write per-bucket runs out coalesced.
// Edge payload: word0 = col(16) | lrow(7) | bucket(9), word1 = fp32 val.
// ---------------------------------------------------------------------------
__global__ __launch_bounds__(512) void bucketize_kernel(
    const int* __restrict__ rows, const int* __restrict__ cols,
    const float* __restrict__ vals, const int* __restrict__ gpartial,
    int2* __restrict__ edges, int* __restrict__ bucket_base,
    int* __restrict__ rowptr) {
    __shared__ int sc[512];            // scan scratch
    __shared__ int ob[512];            // chunk-local exclusive bucket offsets
    __shared__ int gw[NB];             // global write base for this chunk
    __shared__ int cur[NB];            // placement cursors
    __shared__ int2 buf[CHUNK];        // 32 KB
    int t = threadIdx.x;
    int j = blockIdx.x;
    int base = j * CHUNK;
    int M = N_EDGES - base; if (M > CHUNK) M = CHUNK;

    // totals over all chunks + prefix over chunks < j, for bucket t
    int total = 0, pre = 0, cnt = 0;
    if (t < NB) {
        for (int jj = 0; jj < NCHUNK; jj++) {
            int v = gpartial[jj * NB + t];
            total += v;
            pre += (jj < j) ? v : 0;
        }
        cnt = gpartial[j * NB + t];
    }
    // scan 1: exclusive scan of bucket totals -> bucket bases
    sc[t] = total;
    __syncthreads();
    #pragma unroll
    for (int off = 1; off < 512; off <<= 1) {
        int u = (t >= off) ? sc[t - off] : 0;
        __syncthreads();
        sc[t] += u;
        __syncthreads();
    }
    int bexcl = sc[t] - total;
    if (t < NB) { gw[t] = bexcl + pre; cur[t] = 0; }
    if (j == 0) {
        if (t < NB) bucket_base[t] = bexcl;
        if (t == 0) { bucket_base[NB] = N_EDGES; rowptr[N_NODES] = N_EDGES; }
    }
    // scan 2: chunk-local exclusive offsets
    sc[t] = cnt;
    __syncthreads();
    #pragma unroll
    for (int off = 1; off < 512; off <<= 1) {
        int u = (t >= off) ? sc[t - off] : 0;
        __syncthreads();
        sc[t] += u;
        __syncthreads();
    }
    ob[t] = sc[t] - cnt;
    __syncthreads();

    #pragma unroll
    for (int k = 0; k < CHUNK / 512; k++) {
        int e = base + t + k * 512;
        if (e < N_EDGES) {
            int r = rows[e];
            int bb = r >> BUCKET_SHIFT;
            int p = ob[bb] + atomicAdd(&cur[bb], 1);
            buf[p] = make_int2(cols[e] | ((r & 127) << 16) | (bb << 23),
                               __float_as_int(vals[e]));
        }
    }
    __syncthreads();
    for (int i = t; i < M; i += 512) {
        int2 e = buf[i];
        int bb = (int)((uint32)e.x >> 23);
        edges[gw[bb] + (i - ob[bb])] = e;
    }
}

// ---------------------------------------------------------------------------
// Bucket sort: per-bucket LDS counting sort by local row, in place; ALSO
// emits rowptr for its 128 rows. Global-scratch fallback if bucket > CAP_B.
// ---------------------------------------------------------------------------
__global__ __launch_bounds__(256) void bucket_sort_kernel(
    const int* __restrict__ bucket_base, int2* __restrict__ edges,
    int2* __restrict__ scratch, int* __restrict__ rowptr) {
    __shared__ int2 buf[CAP_B];   // 20.5 KB
    __shared__ int2 buf2[CAP_B];  // 20.5 KB
    __shared__ int h[128], o[128], c[128];
    int b = blockIdx.x, t = threadIdx.x;
    int base = bucket_base[b];
    int cnt = bucket_base[b + 1] - base;
    bool fits = (cnt <= CAP_B);
    if (t < 128) h[t] = 0;
    __syncthreads();
    for (int i = t; i < cnt; i += 256) {
        int2 e = edges[base + i];
        if (fits) buf[i] = e; else scratch[base + i] = e;
        atomicAdd(&h[(e.x >> 16) & 127], 1);
    }
    __syncthreads();
    int valh = (t < 128) ? h[t] : 0;
    #pragma unroll
    for (int off = 1; off < 128; off <<= 1) {
        int u = (t >= off && t < 128) ? h[t - off] : 0;
        __syncthreads();
        if (t < 128) h[t] += u;
        __syncthreads();
    }
    if (t < 128) {
        o[t] = h[t] - valh;
        c[t] = 0;
        int i = (b << BUCKET_SHIFT) + t;
        if (i < N_NODES) rowptr[i] = base + h[t] - valh;
    }
    __syncthreads();
    for (int i = t; i < cnt; i += 256) {
        int2 e = fits ? buf[i] : scratch[base + i];
        int lr = (e.x >> 16) & 127;
        int p = o[lr] + atomicAdd(&c[lr], 1);
        if (fits) buf2[p] = e; else edges[base + p] = e;
    }
    __syncthreads();
    if (fits)
        for (int i = t; i < cnt; i += 256) edges[base + i] = buf2[i];
}

// ---------------------------------------------------------------------------
// Gather core: one wave aggregates 8 rows (4 dual-row pairs; lanes 0-31 =
// row A of a pair, lanes 32-63 = row B; lane owns dims hl*4..hl*4+3).
// TWO pairs run concurrently, each 8-deep clamp-padded -> ~16 independent
// gathers in flight per wave. Edge records come from ep[] (LDS-staged,
// broadcast ds_read per half -> no bpermute, no global edge load in chain;
// falls back to global pointer if a block's segment overflows CAP_E).
// Segment bounds are per-lane (uniform within each half).
// ---------------------------------------------------------------------------
template <typename EPT>
__device__ __forceinline__ void gather8rows(
    const uint2* __restrict__ feat2, EPT ep, const int* __restrict__ rowptr,
    int row0, int s0, int wave, int lane, float ac[4][4]) {
    const int half = lane >> 5, hl = lane & 31;
    #pragma unroll
    for (int g = 0; g < 2; g++) {
        int s[2], e[2];
        #pragma unroll
        for (int p = 0; p < 2; p++) {
            int row = row0 + wave * 8 + (g * 2 + p) * 2 + half;
            s[p] = 0; e[p] = 0;
            if (row < N_NODES) {
                s[p] = rowptr[row] - s0;
                e[p] = rowptr[row + 1] - s0;
            }
        }
        int k0 = s[0], k1 = s[1];
        float a00 = 0.f, a01 = 0.f, a02 = 0.f, a03 = 0.f;
        float a10 = 0.f, a11 = 0.f, a12 = 0.f, a13 = 0.f;
        while (k0 < e[0] || k1 < e[1]) {
            int cc[16]; float vv[16];
            #pragma unroll
            for (int u = 0; u < 8; u++) {
                int idx = k0 + u; bool ok = idx < e[0]; idx = ok ? idx : s[0];
                int2 ee = ep[idx];
                cc[u] = ee.x & 0xFFFF;
                vv[u] = ok ? __int_as_float(ee.y) : 0.f;
            }
            #pragma unroll
            for (int u = 0; u < 8; u++) {
                int idx = k1 + u; bool ok = idx < e[1]; idx = ok ? idx : s[1];
                int2 ee = ep[idx];
                cc[8 + u] = ee.x & 0xFFFF;
                vv[8 + u] = ok ? __int_as_float(ee.y) : 0.f;
            }
            uint2 f[16];
            #pragma unroll
            for (int u = 0; u < 16; u++) f[u] = feat2[(size_t)cc[u] * 32 + hl];
            #pragma unroll
            for (int u = 0; u < 8; u++) {
                a00 += vv[u] * bf_lo(f[u].x); a01 += vv[u] * bf_hi(f[u].x);
                a02 += vv[u] * bf_lo(f[u].y); a03 += vv[u] * bf_hi(f[u].y);
            }
            #pragma unroll
            for (int u = 0; u < 8; u++) {
                a10 += vv[8 + u] * bf_lo(f[8 + u].x); a11 += vv[8 + u] * bf_hi(f[8 + u].x);
                a12 += vv[8 + u] * bf_lo(f[8 + u].y); a13 += vv[8 + u] * bf_hi(f[8 + u].y);
            }
            k0 += 8; k1 += 8;
        }
        ac[g * 2 + 0][0] = a00; ac[g * 2 + 0][1] = a01;
        ac[g * 2 + 0][2] = a02; ac[g * 2 + 0][3] = a03;
        ac[g * 2 + 1][0] = a10; ac[g * 2 + 1][1] = a11;
        ac[g * 2 + 1][2] = a12; ac[g * 2 + 1][3] = a13;
    }
}

// ---------------------------------------------------------------------------
// Fused SPMM + double GEMM per 64-row tile (512 thr, 8 waves):
//   stage:   block's sorted edge segment -> LDS (aliases h_s; edges are dead
//            once the gather ends, h_s is only written after the barrier).
//   phase 0: each wave gathers 8 rows into the A-tile (packed bf16).
//   phase 1: h = relu(A @ W1 + b1) via MFMA, wave owns 32 h-cols.
//   phase 2: hw = h @ W2, wave owns 16 hw-cols. Written bf16.
// LDS 51.2 KB -> 3 blocks/CU (24 waves); VGPR budget 128 (launch_bounds 4).
// ---------------------------------------------------------------------------
__global__ __launch_bounds__(512, 4) void spmm_gemm_fused(
    const uint32* __restrict__ xb, const int* __restrict__ rowptr,
    const int2* __restrict__ edges, const ushort16* __restrict__ W1t,
    const ushort16* __restrict__ W2t, const float* __restrict__ b1,
    ushort16* __restrict__ hw) {
    __shared__ ushort16 a_s[64 * 136];  // 17.4 KB
    __shared__ int4 u_s[CAP_E / 2];     // 33.8 KB: esh (phase 0) / h_s (1-2)
    int2* esh = (int2*)u_s;
    ushort16* h_s = (ushort16*)u_s;
    const int tx = threadIdx.x;
    const int wave = tx >> 6, lane = tx & 63;
    const int quad = lane >> 4, l16 = lane & 15;
    const int half = lane >> 5, hl = lane & 31;
    const int row0 = blockIdx.x * 64;
    const uint2* xb2 = (const uint2*)xb;

    // Stage this block's edge segment into LDS (coalesced).
    int rend = row0 + 64; if (rend > N_NODES) rend = N_NODES;
    int s0 = rowptr[row0];
    int cnt = rowptr[rend] - s0;
    bool fits = (cnt <= CAP_E);   // block-uniform
    if (fits)
        for (int i = tx; i < cnt; i += 512) esh[i] = edges[s0 + i];
    __syncthreads();

    // Phase 0: gather 8 rows per wave into the A-tile
    float ac[4][4];
    if (fits) gather8rows(xb2, (const int2*)esh, rowptr, row0, s0, wave, lane, ac);
    else      gather8rows(xb2, edges + s0,       rowptr, row0, s0, wave, lane, ac);
    #pragma unroll
    for (int i = 0; i < 4; i++) {
        int r = wave * 8 + i * 2 + half;
        uint32 lo = (uint32)f2bf(ac[i][0]) | ((uint32)f2bf(ac[i][1]) << 16);
        uint32 hi = (uint32)f2bf(ac[i][2]) | ((uint32)f2bf(ac[i][3]) << 16);
        *(uint2*)&a_s[r * 136 + hl * 4] = make_uint2(lo, hi);
    }

    // Preload stage-1 B fragments: wave owns h-cols [wave*32, wave*32+32)
    short8 bfr1[2][4];  // [ct][kk]
    #pragma unroll
    for (int ct = 0; ct < 2; ct++)
        #pragma unroll
        for (int kk = 0; kk < 4; kk++)
            bfr1[ct][kk] = *(const short8*)
                &W1t[(wave * 32 + ct * 16 + l16) * 128 + kk * 32 + quad * 8];
    __syncthreads();   // all esh reads done; h_s may now overwrite it

    // Phase 1: h = relu(A @ W1 + b1)
    floatx4 acc1[4][2];  // [rs][ct]
    #pragma unroll
    for (int rs = 0; rs < 4; rs++)
        #pragma unroll
        for (int ct = 0; ct < 2; ct++)
            #pragma unroll
            for (int j = 0; j < 4; j++) acc1[rs][ct][j] = 0.f;
    #pragma unroll
    for (int kk = 0; kk < 4; kk++) {
        #pragma unroll
        for (int rs = 0; rs < 4; rs++) {
            short8 af = *(const short8*)&a_s[(rs * 16 + l16) * 136 + kk * 32 + quad * 8];
            #pragma unroll
            for (int ct = 0; ct < 2; ct++)
                acc1[rs][ct] = __builtin_amdgcn_mfma_f32_16x16x32_bf16(
                    af, bfr1[ct][kk], acc1[rs][ct], 0, 0, 0);
        }
    }
    float bv[2];
    #pragma unroll
    for (int ct = 0; ct < 2; ct++) bv[ct] = b1[wave * 32 + ct * 16 + l16];
    #pragma unroll
    for (int rs = 0; rs < 4; rs++)
        #pragma unroll
        for (int ct = 0; ct < 2; ct++)
            #pragma unroll
            for (int reg = 0; reg < 4; reg++) {
                float v = acc1[rs][ct][reg] + bv[ct];
                v = v > 0.f ? v : 0.f;
                h_s[(rs * 16 + quad * 4 + reg) * 264 + wave * 32 + ct * 16 + l16] = f2bf(v);
            }

    // Preload stage-2 B fragments: wave owns hw-cols [wave*16, wave*16+16)
    short8 bfr2[8];
    #pragma unroll
    for (int kk = 0; kk < 8; kk++)
        bfr2[kk] = *(const short8*)
            &W2t[(wave * 16 + l16) * 256 + kk * 32 + quad * 8];
    __syncthreads();

    // Phase 2: hw = h @ W2
    floatx4 acc2[4];
    #pragma unroll
    for (int rs = 0; rs < 4; rs++)
        #pragma unroll
        for (int j = 0; j < 4; j++) acc2[rs][j] = 0.f;
    #pragma unroll
    for (int kk = 0; kk < 8; kk++) {
        #pragma unroll
        for (int rs = 0; rs < 4; rs++) {
            short8 af = *(const short8*)&h_s[(rs * 16 + l16) * 264 + kk * 32 + quad * 8];
            acc2[rs] = __builtin_amdgcn_mfma_f32_16x16x32_bf16(
                af, bfr2[kk], acc2[rs], 0, 0, 0);
        }
    }
    #pragma unroll
    for (int rs = 0; rs < 4; rs++)
        #pragma unroll
        for (int reg = 0; reg < 4; reg++) {
            int row = row0 + rs * 16 + quad * 4 + reg;
            if (row < N_NODES)
                hw[(size_t)row * 128 + wave * 16 + l16] = f2bf(acc2[rs][reg]);
        }
}

// ---------------------------------------------------------------------------
// Final spmm: out = A @ hw + b2 (fp32 out). Same 64-row/8-wave shape with
// LDS-staged edges; 33.8 KB LDS + 512 thr -> 4 blocks/CU (32 waves, 100%).
// ---------------------------------------------------------------------------
__global__ __launch_bounds__(512, 4) void spmm_out_kernel(
    const uint32* __restrict__ feat, const int* __restrict__ rowptr,
    const int2* __restrict__ edges, const float* __restrict__ bias,
    float* __restrict__ out) {
    __shared__ int2 esh[CAP_E];   // 33.8 KB
    const int tx = threadIdx.x;
    const int wave = tx >> 6, lane = tx & 63;
    const int half = lane >> 5, hl = lane & 31;
    const int row0 = blockIdx.x * 64;
    const uint2* f2 = (const uint2*)feat;

    int rend = row0 + 64; if (rend > N_NODES) rend = N_NODES;
    int s0 = rowptr[row0];
    int cnt = rowptr[rend] - s0;
    bool fits = (cnt <= CAP_E);
    if (fits)
        for (int i = tx; i < cnt; i += 512) esh[i] = edges[s0 + i];
    __syncthreads();

    float ac[4][4];
    if (fits) gather8rows(f2, (const int2*)esh, rowptr, row0, s0, wave, lane, ac);
    else      gather8rows(f2, edges + s0,       rowptr, row0, s0, wave, lane, ac);

    float4 b = ((const float4*)bias)[hl];
    #pragma unroll
    for (int i = 0; i < 4; i++) {
        int row = row0 + wave * 8 + i * 2 + half;
        if (row < N_NODES)
            ((float4*)out)[(size_t)row * 32 + hl] =
                make_float4(ac[i][0] + b.x, ac[i][1] + b.y,
                            ac[i][2] + b.z, ac[i][3] + b.w);
    }
}

extern "C" void kernel_launch(void* const* d_in, const int* in_sizes, int n_in,
                              void* d_out, int out_size, void* d_ws, size_t ws_size,
                              hipStream_t stream) {
    const float* x = (const float*)d_in[0];
    const float* adj_vals = (const float*)d_in[1];
    const int* adj_row = (const int*)d_in[2];
    const int* adj_col = (const int*)d_in[3];
    const float* W1 = (const float*)d_in[4];
    const float* b1 = (const float*)d_in[5];
    const float* W2 = (const float*)d_in[6];
    const float* b2 = (const float*)d_in[7];
    float* out = (float*)d_out;

    // Workspace layout (~39 MB):
    char* ws = (char*)d_ws;
    uint32*   xb       = (uint32*)  (ws + 0);            // 12.8 MB (bf16 x-norm)
    ushort16* hw       = (ushort16*)(ws + 12800000);     // 12.8 MB (bf16)
    int2*     edges    = (int2*)    (ws + 25600000);     //  6.4 MB
    int2*     scratch  = (int2*)    (ws + 32000000);     //  6.4 MB (fallback only)
    int*      gpartial = (int*)     (ws + 38400000);     //  306 KB
    int*      rowptr   = (int*)     (ws + 38713344);     //  200 KB
    int*      bbase    = (int*)     (ws + 38914048);     //  1.6 KB
    ushort16* W1t      = (ushort16*)(ws + 38918144);     //   64 KB
    ushort16* W2t      = (ushort16*)(ws + 38983680);     //   64 KB

    // 1. prep: x-hat bf16 + transposed bf16 weights + per-chunk bucket hists
    hipLaunchKernelGGL(prep_kernel, dim3(NORM_BLOCKS + CONV_BLOCKS + NCHUNK),
                       dim3(256), 0, stream, x, xb, W1, W2, W1t, W2t,
                       adj_row, gpartial);

    // 2. bucketize (scan folded in, atomic-free deterministic placement)
    hipLaunchKernelGGL(bucketize_kernel, dim3(NCHUNK), dim3(512),
                       0, stream, adj_row, adj_col, adj_vals, gpartial,
                       edges, bbase, rowptr);

    // 3. per-bucket sort (emits rowptr)
    hipLaunchKernelGGL(bucket_sort_kernel, dim3(NB), dim3(256),
                       0, stream, bbase, edges, scratch, rowptr);

    // 4. hw = relu((A @ x-hat) @ W1 + b1) @ W2   [fused spmm + MFMA GEMMs]
    hipLaunchKernelGGL(spmm_gemm_fused, dim3((N_NODES + 63) / 64), dim3(512),
                       0, stream, xb, rowptr, edges, W1t, W2t, b1, hw);

    // 5. out = A @ hw + b2
    hipLaunchKernelGGL(spmm_out_kernel, dim3((N_NODES + 63) / 64), dim3(512),
                       0, stream, (const uint32*)hw, rowptr, edges, b2, out);
}

// Round 4
// 208.159 us; speedup vs baseline: 1.2214x; 1.0690x over previous
//
#include <hip/hip_runtime.h>

// Problem constants (fixed by the reference).
#define N_NODES 50000
#define N_EDGES 800000
#define X_DIM 128
#define H_DIM 256
#define Y_DIM 128

typedef unsigned int uint32;
typedef unsigned short ushort16;
typedef __attribute__((ext_vector_type(8))) short short8;
typedef __attribute__((ext_vector_type(4))) float floatx4;

// bf16 helpers (round-to-nearest-even)
__device__ inline ushort16 f2bf(float f) {
    uint32 u = __float_as_uint(f);
    return (ushort16)((u + 0x7FFFu + ((u >> 16) & 1u)) >> 16);
}
__device__ inline float bf_lo(uint32 u) { return __uint_as_float(u << 16); }
__device__ inline float bf_hi(uint32 u) { return __uint_as_float(u & 0xFFFF0000u); }

// Bucket geometry: 391 buckets of 128 rows; 196 chunks of 4096 edges.
#define BUCKET_SHIFT 7
#define NB 391              // ceil(50000/128)
#define CHUNK 4096
#define NCHUNK 196          // ceil(800000/4096)
#define CAP_B 2560          // LDS capacity per bucket (mean 2046)

#define NORM_BLOCKS 12500   // N_NODES*64/256
#define CONV_BLOCKS 256     // 65536/256

// ---------------------------------------------------------------------------
// Prep (fused): row-normalize x -> bf16; transpose-convert W1,W2 to bf16;
// per-chunk bucket histograms -> gpartial[chunk][bucket] (no global atomics).
// ---------------------------------------------------------------------------
__global__ __launch_bounds__(256) void prep_kernel(
    const float* __restrict__ x, uint32* __restrict__ xb,
    const float* __restrict__ W1, const float* __restrict__ W2,
    ushort16* __restrict__ W1t, ushort16* __restrict__ W2t,
    const int* __restrict__ rows, int* __restrict__ gpartial) {
    int b = blockIdx.x;
    if (b < NORM_BLOCKS) {
        int row = (b * 256 + threadIdx.x) >> 6;  // exact: 12500*4 = 50000 rows
        int lane = threadIdx.x & 63;
        float2 v = ((const float2*)x)[(size_t)row * 64 + lane];
        float s = v.x + v.y;
        #pragma unroll
        for (int off = 32; off > 0; off >>= 1) s += __shfl_xor(s, off, 64);
        float inv = 1.0f / (s + 1e-4f);
        uint32 lo = (uint32)f2bf(v.x * inv);
        uint32 hi = (uint32)f2bf(v.y * inv);
        xb[(size_t)row * 64 + lane] = lo | (hi << 16);
    } else if (b < NORM_BLOCKS + CONV_BLOCKS) {
        int t = (b - NORM_BLOCKS) * 256 + threadIdx.x;  // 0..65535
        if (t < X_DIM * H_DIM) {
            int n = t >> 7, k = t & 127;           // W1t[n][k] = W1[k][n]
            W1t[t] = f2bf(W1[k * H_DIM + n]);
        } else {
            int u = t - X_DIM * H_DIM;
            int y = u >> 8, k = u & 255;           // W2t[y][k] = W2[k][y]
            W2t[u] = f2bf(W2[k * Y_DIM + y]);
        }
    } else {
        __shared__ int h[NB];
        int j = b - NORM_BLOCKS - CONV_BLOCKS;     // chunk id 0..195
        int t = threadIdx.x;
        for (int i = t; i < NB; i += 256) h[i] = 0;
        __syncthreads();
        int base = j * CHUNK;
        #pragma unroll
        for (int k = 0; k < CHUNK / 256; k++) {
            int e = base + t + k * 256;
            if (e < N_EDGES) atomicAdd(&h[rows[e] >> BUCKET_SHIFT], 1);
        }
        __syncthreads();
        for (int i = t; i < NB; i += 256) gpartial[j * NB + i] = h[i];
    }
}

// ---------------------------------------------------------------------------
// Bucket scan (1 block): totals = sum_j gpartial[j][b]; exclusive scan ->
// bucket_base (392 entries) + bcursor seed; rowptr[N] = E.
// ---------------------------------------------------------------------------
__global__ __launch_bounds__(512) void bucket_scan_kernel(
    const int* __restrict__ gpartial, int* __restrict__ bucket_base,
    int* __restrict__ bcursor, int* __restrict__ rowptr) {
    __shared__ int s[512];
    int t = threadIdx.x;
    int total = 0;
    if (t < NB) {
        #pragma unroll 4
        for (int j = 0; j < NCHUNK; j++) total += gpartial[j * NB + t];
    }
    s[t] = total;
    __syncthreads();
    #pragma unroll
    for (int off = 1; off < 512; off <<= 1) {
        int u = (t >= off) ? s[t - off] : 0;
        __syncthreads();
        s[t] += u;
        __syncthreads();
    }
    if (t < NB) {
        int excl = s[t] - total;
        bucket_base[t] = excl;
        bcursor[t] = excl;
    }
    if (t == 0) { bucket_base[NB] = N_EDGES; rowptr[N_NODES] = N_EDGES; }
}

// ---------------------------------------------------------------------------
// Bucketize: compact each 4096-edge chunk into per-bucket LDS runs (offsets
// from gpartial), reserve global ranges via one atomic per bucket, copy out.
// Edge payload: word0 = col(16) | lrow(7) | bucket(9), word1 = fp32 val.
// ---------------------------------------------------------------------------
__global__ __launch_bounds__(512) void bucketize_kernel(
    const int* __restrict__ rows, const int* __restrict__ cols,
    const float* __restrict__ vals, const int* __restrict__ gpartial,
    int* __restrict__ bcursor, int2* __restrict__ edges) {
    __shared__ int ob[512];            // exclusive chunk-local bucket offsets
    __shared__ int c[NB];              // placement cursors
    __shared__ int g[NB];              // reserved global bases
    __shared__ int2 buf[CHUNK];        // 32 KB
    int t = threadIdx.x;
    int j = blockIdx.x;
    int base = j * CHUNK;
    int M = N_EDGES - base; if (M > CHUNK) M = CHUNK;
    int cnt = (t < NB) ? gpartial[j * NB + t] : 0;
    ob[t] = cnt;
    __syncthreads();
    #pragma unroll
    for (int off = 1; off < 512; off <<= 1) {
        int u = (t >= off) ? ob[t - off] : 0;
        __syncthreads();
        ob[t] += u;
        __syncthreads();
    }
    ob[t] -= cnt;  // exclusive (own slot only)
    if (t < NB) {
        c[t] = 0;
        g[t] = (cnt > 0) ? atomicAdd(&bcursor[t], cnt) : 0;
    }
    __syncthreads();
    #pragma unroll
    for (int k = 0; k < CHUNK / 512; k++) {
        int e = base + t + k * 512;
        if (e < N_EDGES) {
            int r = rows[e];
            int bb = r >> BUCKET_SHIFT;
            int p = ob[bb] + atomicAdd(&c[bb], 1);
            buf[p] = make_int2(cols[e] | ((r & 127) << 16) | (bb << 23),
                               __float_as_int(vals[e]));
        }
    }
    __syncthreads();
    for (int i = t; i < M; i += 512) {
        int2 e = buf[i];
        int bb = (int)((uint32)e.x >> 23);
        edges[g[bb] + (i - ob[bb])] = e;
    }
}

// ---------------------------------------------------------------------------
// Bucket sort: per-bucket LDS counting sort by local row, in place; ALSO
// emits rowptr for its 128 rows. Global-scratch fallback if bucket > CAP_B.
// ---------------------------------------------------------------------------
__global__ __launch_bounds__(256) void bucket_sort_kernel(
    const int* __restrict__ bucket_base, int2* __restrict__ edges,
    int2* __restrict__ scratch, int* __restrict__ rowptr) {
    __shared__ int2 buf[CAP_B];   // 20.5 KB
    __shared__ int2 buf2[CAP_B];  // 20.5 KB
    __shared__ int h[128], o[128], c[128];
    int b = blockIdx.x, t = threadIdx.x;
    int base = bucket_base[b];
    int cnt = bucket_base[b + 1] - base;
    bool fits = (cnt <= CAP_B);
    if (t < 128) h[t] = 0;
    __syncthreads();
    for (int i = t; i < cnt; i += 256) {
        int2 e = edges[base + i];
        if (fits) buf[i] = e; else scratch[base + i] = e;
        atomicAdd(&h[(e.x >> 16) & 127], 1);
    }
    __syncthreads();
    int valh = (t < 128) ? h[t] : 0;
    #pragma unroll
    for (int off = 1; off < 128; off <<= 1) {
        int u = (t >= off && t < 128) ? h[t - off] : 0;
        __syncthreads();
        if (t < 128) h[t] += u;
        __syncthreads();
    }
    if (t < 128) {
        o[t] = h[t] - valh;
        c[t] = 0;
        int i = (b << BUCKET_SHIFT) + t;
        if (i < N_NODES) rowptr[i] = base + h[t] - valh;
    }
    __syncthreads();
    for (int i = t; i < cnt; i += 256) {
        int2 e = fits ? buf[i] : scratch[base + i];
        int lr = (e.x >> 16) & 127;
        int p = o[lr] + atomicAdd(&c[lr], 1);
        if (fits) buf2[p] = e; else edges[base + p] = e;
    }
    __syncthreads();
    if (fits)
        for (int i = t; i < cnt; i += 256) edges[base + i] = buf2[i];
}

// ---------------------------------------------------------------------------
// Quad-row spmm accumulator: wave = 4 groups of 16 lanes; group g processes
// its own row, lane owns dims g16*8..g16*8+7 via uint4 (= 8 bf16, 16 B).
// Halves VMEM instructions AND addresses per edge vs dual-row uint2
// (16 addr / 256 B row instead of 32): the gather is request-rate bound.
// 8-wide edge unroll: 8 independent 16 B gathers in flight per group.
// start/end are per-lane (uniform within each 16-lane group).
// ---------------------------------------------------------------------------
__device__ __forceinline__ void spmm_row4(const uint4* __restrict__ feat4,
                                          const int2* __restrict__ edges,
                                          int start, int end, int lane,
                                          float A[8]) {
    const int g16 = lane & 15;    // lane-in-group
    const int bsrc = lane & 48;   // shfl source base for my group
    int cur = start;
    while (__any(cur < end)) {
        int n = end - cur;
        n = n < 0 ? 0 : (n > 16 ? 16 : n);
        int2 ev = make_int2(0, 0);
        if (g16 < n) ev = edges[cur + g16];
        int c = ev.x & 0xFFFF;
        float v = __int_as_float(ev.y);
        int n0 = __shfl(n, 0, 64), n1 = __shfl(n, 16, 64);
        int n2 = __shfl(n, 32, 64), n3 = __shfl(n, 48, 64);
        int nm = max(max(n0, n1), max(n2, n3));
        int jm = (nm + 7) & ~7;
        for (int j = 0; j < jm; j += 8) {
            uint4 f[8];
            float vv[8];
            #pragma unroll
            for (int u = 0; u < 8; u++) {
                int cc = __shfl(c, bsrc + j + u, 64);
                vv[u] = __shfl(v, bsrc + j + u, 64);
                f[u] = feat4[(size_t)cc * 16 + g16];
            }
            #pragma unroll
            for (int u = 0; u < 8; u++) {
                A[0] += vv[u] * bf_lo(f[u].x); A[1] += vv[u] * bf_hi(f[u].x);
                A[2] += vv[u] * bf_lo(f[u].y); A[3] += vv[u] * bf_hi(f[u].y);
                A[4] += vv[u] * bf_lo(f[u].z); A[5] += vv[u] * bf_hi(f[u].z);
                A[6] += vv[u] * bf_lo(f[u].w); A[7] += vv[u] * bf_hi(f[u].w);
            }
        }
        cur += n;
    }
}

// ---------------------------------------------------------------------------
// Fused SPMM + double GEMM per 64-row tile (512 thr, 8 waves):
//   phase 0: each wave gathers 8 rows (2 passes x 4 rows, quad-row) of
//            agg1 = A @ x-hat straight into the LDS A-tile (packed bf16).
//   phase 1: h = relu(A @ W1 + b1) via MFMA, wave owns 32 h-cols
//            (B-fragments loaded AFTER phase 0 to free gather registers).
//   phase 2: hw = h @ W2, wave owns 16 hw-cols. Written bf16.
// LDS 51.2 KB -> 3 blocks/CU (24 waves); VGPR budget 128 (launch_bounds 4).
// ---------------------------------------------------------------------------
__global__ __launch_bounds__(512, 4) void spmm_gemm_fused(
    const uint32* __restrict__ xb, const int* __restrict__ rowptr,
    const int2* __restrict__ edges, const ushort16* __restrict__ W1t,
    const ushort16* __restrict__ W2t, const float* __restrict__ b1,
    ushort16* __restrict__ hw) {
    __shared__ ushort16 a_s[64 * 136];  // 17.4 KB
    __shared__ ushort16 h_s[64 * 264];  // 33.8 KB
    const int tx = threadIdx.x;
    const int wave = tx >> 6, lane = tx & 63;
    const int quad = lane >> 4, l16 = lane & 15;
    const int row0 = blockIdx.x * 64;
    const uint4* xb4 = (const uint4*)xb;

    // Phase 0: gather 8 rows per wave (4 at a time, quad-row) into the A-tile
    for (int i = 0; i < 2; i++) {
        int r = wave * 8 + i * 4 + quad;
        int row = row0 + r;
        int s = 0, e = 0;
        if (row < N_NODES) { s = rowptr[row]; e = rowptr[row + 1]; }
        float A[8] = {0.f, 0.f, 0.f, 0.f, 0.f, 0.f, 0.f, 0.f};
        spmm_row4(xb4, edges, s, e, lane, A);
        uint4 pk;
        pk.x = (uint32)f2bf(A[0]) | ((uint32)f2bf(A[1]) << 16);
        pk.y = (uint32)f2bf(A[2]) | ((uint32)f2bf(A[3]) << 16);
        pk.z = (uint32)f2bf(A[4]) | ((uint32)f2bf(A[5]) << 16);
        pk.w = (uint32)f2bf(A[6]) | ((uint32)f2bf(A[7]) << 16);
        *(uint4*)&a_s[r * 136 + l16 * 8] = pk;
    }

    // Preload stage-1 B fragments AFTER the gather (register pressure):
    // wave owns h-cols [wave*32, wave*32+32)
    short8 bfr1[2][4];  // [ct][kk]
    #pragma unroll
    for (int ct = 0; ct < 2; ct++)
        #pragma unroll
        for (int kk = 0; kk < 4; kk++)
            bfr1[ct][kk] = *(const short8*)
                &W1t[(wave * 32 + ct * 16 + l16) * 128 + kk * 32 + quad * 8];
    __syncthreads();

    // Phase 1: h = relu(A @ W1 + b1)
    floatx4 acc1[4][2];  // [rs][ct]
    #pragma unroll
    for (int rs = 0; rs < 4; rs++)
        #pragma unroll
        for (int ct = 0; ct < 2; ct++)
            #pragma unroll
            for (int j = 0; j < 4; j++) acc1[rs][ct][j] = 0.f;
    #pragma unroll
    for (int kk = 0; kk < 4; kk++) {
        #pragma unroll
        for (int rs = 0; rs < 4; rs++) {
            short8 af = *(const short8*)&a_s[(rs * 16 + l16) * 136 + kk * 32 + quad * 8];
            #pragma unroll
            for (int ct = 0; ct < 2; ct++)
                acc1[rs][ct] = __builtin_amdgcn_mfma_f32_16x16x32_bf16(
                    af, bfr1[ct][kk], acc1[rs][ct], 0, 0, 0);
        }
    }
    float bv[2];
    #pragma unroll
    for (int ct = 0; ct < 2; ct++) bv[ct] = b1[wave * 32 + ct * 16 + l16];
    #pragma unroll
    for (int rs = 0; rs < 4; rs++)
        #pragma unroll
        for (int ct = 0; ct < 2; ct++)
            #pragma unroll
            for (int reg = 0; reg < 4; reg++) {
                float v = acc1[rs][ct][reg] + bv[ct];
                v = v > 0.f ? v : 0.f;
                h_s[(rs * 16 + quad * 4 + reg) * 264 + wave * 32 + ct * 16 + l16] = f2bf(v);
            }

    // Preload stage-2 B fragments: wave owns hw-cols [wave*16, wave*16+16)
    short8 bfr2[8];
    #pragma unroll
    for (int kk = 0; kk < 8; kk++)
        bfr2[kk] = *(const short8*)
            &W2t[(wave * 16 + l16) * 256 + kk * 32 + quad * 8];
    __syncthreads();

    // Phase 2: hw = h @ W2
    floatx4 acc2[4];
    #pragma unroll
    for (int rs = 0; rs < 4; rs++)
        #pragma unroll
        for (int j = 0; j < 4; j++) acc2[rs][j] = 0.f;
    #pragma unroll
    for (int kk = 0; kk < 8; kk++) {
        #pragma unroll
        for (int rs = 0; rs < 4; rs++) {
            short8 af = *(const short8*)&h_s[(rs * 16 + l16) * 264 + kk * 32 + quad * 8];
            acc2[rs] = __builtin_amdgcn_mfma_f32_16x16x32_bf16(
                af, bfr2[kk], acc2[rs], 0, 0, 0);
        }
    }
    #pragma unroll
    for (int rs = 0; rs < 4; rs++)
        #pragma unroll
        for (int reg = 0; reg < 4; reg++) {
            int row = row0 + rs * 16 + quad * 4 + reg;
            if (row < N_NODES)
                hw[(size_t)row * 128 + wave * 16 + l16] = f2bf(acc2[rs][reg]);
        }
}

// ---------------------------------------------------------------------------
// Final spmm: out = A @ hw + b2 (fp32 out). One wave per 4 rows (quad-row).
// Grid exact: 3125 blocks x 4 waves x 4 rows = 50000.
// ---------------------------------------------------------------------------
__global__ __launch_bounds__(256) void spmm_out_kernel(
    const uint32* __restrict__ feat, const int* __restrict__ rowptr,
    const int2* __restrict__ edges, const float* __restrict__ bias,
    float* __restrict__ out) {
    int w = (blockIdx.x * blockDim.x + threadIdx.x) >> 6;
    int lane = threadIdx.x & 63;
    int quad = lane >> 4, g16 = lane & 15;
    int row = w * 4 + quad;  // always < N_NODES (exact grid)
    int s = rowptr[row], e = rowptr[row + 1];
    float A[8] = {0.f, 0.f, 0.f, 0.f, 0.f, 0.f, 0.f, 0.f};
    spmm_row4((const uint4*)feat, edges, s, e, lane, A);
    float4 b0 = ((const float4*)bias)[g16 * 2];
    float4 b1 = ((const float4*)bias)[g16 * 2 + 1];
    ((float4*)out)[(size_t)row * 32 + g16 * 2] =
        make_float4(A[0] + b0.x, A[1] + b0.y, A[2] + b0.z, A[3] + b0.w);
    ((float4*)out)[(size_t)row * 32 + g16 * 2 + 1] =
        make_float4(A[4] + b1.x, A[5] + b1.y, A[6] + b1.z, A[7] + b1.w);
}

extern "C" void kernel_launch(void* const* d_in, const int* in_sizes, int n_in,
                              void* d_out, int out_size, void* d_ws, size_t ws_size,
                              hipStream_t stream) {
    const float* x = (const float*)d_in[0];
    const float* adj_vals = (const float*)d_in[1];
    const int* adj_row = (const int*)d_in[2];
    const int* adj_col = (const int*)d_in[3];
    const float* W1 = (const float*)d_in[4];
    const float* b1 = (const float*)d_in[5];
    const float* W2 = (const float*)d_in[6];
    const float* b2 = (const float*)d_in[7];
    float* out = (float*)d_out;

    // Workspace layout (~39 MB):
    char* ws = (char*)d_ws;
    uint32*   xb       = (uint32*)  (ws + 0);            // 12.8 MB (bf16 x-norm)
    ushort16* hw       = (ushort16*)(ws + 12800000);     // 12.8 MB (bf16)
    int2*     edges    = (int2*)    (ws + 25600000);     //  6.4 MB
    int2*     scratch  = (int2*)    (ws + 32000000);     //  6.4 MB (fallback only)
    int*      gpartial = (int*)     (ws + 38400000);     //  306 KB
    int*      rowptr   = (int*)     (ws + 38713344);     //  200 KB
    int*      bbase    = (int*)     (ws + 38914048);     //  1.6 KB
    int*      bcursor  = (int*)     (ws + 38916096);     //  1.6 KB
    ushort16* W1t      = (ushort16*)(ws + 38918144);     //   64 KB
    ushort16* W2t      = (ushort16*)(ws + 38983680);     //   64 KB

    // 1. prep: x-hat bf16 + transposed bf16 weights + per-chunk bucket hists
    hipLaunchKernelGGL(prep_kernel, dim3(NORM_BLOCKS + CONV_BLOCKS + NCHUNK),
                       dim3(256), 0, stream, x, xb, W1, W2, W1t, W2t,
                       adj_row, gpartial);

    // 2. bucket bases (scan of 391 totals)
    hipLaunchKernelGGL(bucket_scan_kernel, dim3(1), dim3(512),
                       0, stream, gpartial, bbase, bcursor, rowptr);

    // 3. bucketize (coalesced) + per-bucket sort (emits rowptr)
    hipLaunchKernelGGL(bucketize_kernel, dim3(NCHUNK), dim3(512),
                       0, stream, adj_row, adj_col, adj_vals, gpartial, bcursor, edges);
    hipLaunchKernelGGL(bucket_sort_kernel, dim3(NB), dim3(256),
                       0, stream, bbase, edges, scratch, rowptr);

    // 4. hw = relu((A @ x-hat) @ W1 + b1) @ W2   [fused spmm + MFMA GEMMs]
    hipLaunchKernelGGL(spmm_gemm_fused, dim3((N_NODES + 63) / 64), dim3(512),
                       0, stream, xb, rowptr, edges, W1t, W2t, b1, hw);

    // 5. out = A @ hw + b2
    hipLaunchKernelGGL(spmm_out_kernel, dim3(N_NODES / 16), dim3(256),
                       0, stream, (const uint32*)hw, rowptr, edges, b2, out);
}